// Round 2
// baseline (3189.917 us; speedup 1.0000x reference)
//
#include <hip/hip_runtime.h>
#include <hip/hip_bf16.h>
#include <math.h>

constexpr int kN   = 20000;
constexpr int kE   = 256000;
constexpr int kESM = 1280;
constexpr int kHC  = 1024;

// ---------------------------------------------------------------------------
// K1: degree + weighted-degree via atomics
// ---------------------------------------------------------------------------
__global__ __launch_bounds__(256) void deg_kernel(
    const int* __restrict__ dst, const float* __restrict__ ew,
    int* __restrict__ deg, float* __restrict__ wsum)
{
    int e = blockIdx.x * 256 + threadIdx.x;
    if (e < kE) {
        int d = dst[e];
        atomicAdd(&deg[d], 1);
        atomicAdd(&wsum[d], ew[e]);
    }
}

// ---------------------------------------------------------------------------
// K2: single-block exclusive scan of deg -> offsets; loop_attr = wsum/max(deg,1)
// ---------------------------------------------------------------------------
__global__ __launch_bounds__(256) void scan_kernel(
    const int* __restrict__ deg, float* __restrict__ loopat,
    int* __restrict__ offsets)
{
    __shared__ int s[256];
    int tid = threadIdx.x;
    int base = 0;
    if (tid == 0) offsets[0] = 0;
    for (int t0 = 0; t0 < kN; t0 += 256) {
        int i = t0 + tid;
        int d = (i < kN) ? deg[i] : 0;
        if (i < kN) {
            float w = loopat[i];
            loopat[i] = w / fmaxf((float)d, 1.0f);
        }
        s[tid] = d;
        int v = d;
        for (int off = 1; off < 256; off <<= 1) {
            __syncthreads();
            int add = (tid >= off) ? s[tid - off] : 0;
            __syncthreads();
            v += add;
            s[tid] = v;
        }
        __syncthreads();
        if (i < kN) offsets[i + 1] = base + v;
        base += s[255];
        __syncthreads();
    }
}

// ---------------------------------------------------------------------------
// K3: scatter edges into dst-sorted order
// ---------------------------------------------------------------------------
__global__ __launch_bounds__(256) void sort_kernel(
    const int* __restrict__ src, const int* __restrict__ dst,
    const float* __restrict__ ew, const int* __restrict__ offsets,
    int* __restrict__ cnt, int* __restrict__ ssrc, float* __restrict__ sew)
{
    int e = blockIdx.x * 256 + threadIdx.x;
    if (e < kE) {
        int d = dst[e];
        int p = offsets[d] + atomicAdd(&cnt[d], 1);
        ssrc[p] = src[e];
        sew[p]  = ew[e];
    }
}

// ---------------------------------------------------------------------------
// K4/K7: fp32 tiled GEMM, 128x128 tile, BK=16, 256 threads, 8x8 micro-tile.
// C = epilogue(A@B [+ A2@B2] + bias [, relu] [, +resid])
// ---------------------------------------------------------------------------
#define BM 128
#define BN 128
#define BK 16

__global__ __launch_bounds__(256) void gemm_kernel(
    const float* __restrict__ A,  const float* __restrict__ B,
    const float* __restrict__ A2, const float* __restrict__ B2,
    const float* __restrict__ bias, const float* __restrict__ resid,
    float* __restrict__ C, int M, int N, int K, int do_relu)
{
    __shared__ float As[BK][BM];
    __shared__ float Bs[BK][BN];

    const int tid = threadIdx.x;
    const int bm = blockIdx.y, bn = blockIdx.x;
    const int row0 = bm * BM, col0 = bn * BN;
    const int tx = tid & 15, ty = tid >> 4;

    float acc[8][8];
#pragma unroll
    for (int i = 0; i < 8; ++i)
#pragma unroll
        for (int j = 0; j < 8; ++j) acc[i][j] = 0.0f;

    const int arow  = tid >> 1;        // 0..127
    const int akoff = (tid & 1) * 8;   // 0 or 8
    const int bkr   = tid >> 4;        // 0..15
    const int bcol  = (tid & 15) * 8;  // 0..120

    for (int pair = 0; pair < 2; ++pair) {
        const float* Ap = pair ? A2 : A;
        const float* Bp = pair ? B2 : B;
        if (!Ap) break;
        for (int k0 = 0; k0 < K; k0 += BK) {
            float4 a0 = make_float4(0.f, 0.f, 0.f, 0.f);
            float4 a1 = a0;
            int gr = row0 + arow;
            if (gr < M) {
                const float* aptr = Ap + (size_t)gr * K + k0 + akoff;
                a0 = *(const float4*)aptr;
                a1 = *(const float4*)(aptr + 4);
            }
            const float* bptr = Bp + (size_t)(k0 + bkr) * N + col0 + bcol;
            float4 b0 = *(const float4*)bptr;
            float4 b1 = *(const float4*)(bptr + 4);

            __syncthreads();
            As[akoff + 0][arow] = a0.x;
            As[akoff + 1][arow] = a0.y;
            As[akoff + 2][arow] = a0.z;
            As[akoff + 3][arow] = a0.w;
            As[akoff + 4][arow] = a1.x;
            As[akoff + 5][arow] = a1.y;
            As[akoff + 6][arow] = a1.z;
            As[akoff + 7][arow] = a1.w;
            *(float4*)&Bs[bkr][bcol]     = b0;
            *(float4*)&Bs[bkr][bcol + 4] = b1;
            __syncthreads();

#pragma unroll
            for (int kk = 0; kk < BK; ++kk) {
                float4 a0r = *(const float4*)&As[kk][ty * 8];
                float4 a1r = *(const float4*)&As[kk][ty * 8 + 4];
                float4 b0r = *(const float4*)&Bs[kk][tx * 4];
                float4 b1r = *(const float4*)&Bs[kk][64 + tx * 4];
                float ar[8] = {a0r.x, a0r.y, a0r.z, a0r.w, a1r.x, a1r.y, a1r.z, a1r.w};
                float br[8] = {b0r.x, b0r.y, b0r.z, b0r.w, b1r.x, b1r.y, b1r.z, b1r.w};
#pragma unroll
                for (int i = 0; i < 8; ++i)
#pragma unroll
                    for (int j = 0; j < 8; ++j)
                        acc[i][j] = fmaf(ar[i], br[j], acc[i][j]);
            }
        }
    }

#pragma unroll
    for (int i = 0; i < 8; ++i) {
        int gr = row0 + ty * 8 + i;
        if (gr >= M) break;
#pragma unroll
        for (int half = 0; half < 2; ++half) {
            int gc = col0 + half * 64 + tx * 4;
            float4 out;
            float* o = &out.x;
            const float* rrow = resid ? (resid + (size_t)gr * N + gc) : nullptr;
#pragma unroll
            for (int j = 0; j < 4; ++j) {
                float v = acc[i][half * 4 + j];
                if (bias) v += bias[gc + j];
                if (do_relu) v = fmaxf(v, 0.0f);
                if (rrow) v += rrow[j];
                o[j] = v;
            }
            *(float4*)&C[(size_t)gr * N + gc] = out;
        }
    }
}

// ---------------------------------------------------------------------------
// K5: fused per-node GAT, wave==head mapping. Thread t owns columns
// [4t,4t+4) so wave w (lanes 64w..64w+63) owns head w's 256 columns.
// Online softmax over incoming edges + self-loop; logit reduce is a pure
// intra-wave shfl tree: NO barriers, NO LDS in the edge loop.
// ---------------------------------------------------------------------------
__global__ __launch_bounds__(256) void gat_kernel(
    const float* __restrict__ xl, const float* __restrict__ xr,
    const int* __restrict__ ssrc, const float* __restrict__ sew,
    const int* __restrict__ offsets, const float* __restrict__ loopat,
    const float* __restrict__ We, const float* __restrict__ att,
    const float* __restrict__ bgat, float* __restrict__ hout)
{
    const int n = blockIdx.x;
    const int base = threadIdx.x * 4;

    const float4 xr4 = *(const float4*)&xr[(size_t)n * kHC + base];
    const float4 We4 = *(const float4*)&We[base];
    const float4 at4 = *(const float4*)&att[base];

    float M = -INFINITY, D = 0.f;
    float4 acc = make_float4(0.f, 0.f, 0.f, 0.f);

    const int beg = offsets[n], end = offsets[n + 1];
    for (int e = beg; e <= end; ++e) {   // inclusive: last iter = self-loop
        int s; float w;
        if (e < end) { s = ssrc[e]; w = sew[e]; }
        else         { s = n;       w = loopat[n]; }

        const float4 xls = *(const float4*)&xl[(size_t)s * kHC + base];
        float m0 = xls.x + xr4.x + w * We4.x;
        float m1 = xls.y + xr4.y + w * We4.y;
        float m2 = xls.z + xr4.z + w * We4.z;
        float m3 = xls.w + xr4.w + w * We4.w;
        m0 = (m0 >= 0.f) ? m0 : 0.2f * m0;
        m1 = (m1 >= 0.f) ? m1 : 0.2f * m1;
        m2 = (m2 >= 0.f) ? m2 : 0.2f * m2;
        m3 = (m3 >= 0.f) ? m3 : 0.2f * m3;
        float p = m0 * at4.x + m1 * at4.y + m2 * at4.z + m3 * at4.w;
#pragma unroll
        for (int o = 32; o >= 1; o >>= 1) p += __shfl_xor(p, o, 64);

        float newM  = fmaxf(M, p);
        float scale = __expf(M - newM);   // exp(-inf)=0 on first edge
        float wexp  = __expf(p - newM);
        D     = D * scale + wexp;
        acc.x = acc.x * scale + wexp * xls.x;
        acc.y = acc.y * scale + wexp * xls.y;
        acc.z = acc.z * scale + wexp * xls.z;
        acc.w = acc.w * scale + wexp * xls.w;
        M = newM;
    }

    const float inv = 1.0f / (D + 1e-16f);
    float g0 = acc.x * inv + bgat[base + 0];
    float g1 = acc.y * inv + bgat[base + 1];
    float g2 = acc.z * inv + bgat[base + 2];
    float g3 = acc.w * inv + bgat[base + 3];
    float4 hv;
    hv.x = (g0 > 0.f) ? g0 : expm1f(g0);
    hv.y = (g1 > 0.f) ? g1 : expm1f(g1);
    hv.z = (g2 > 0.f) ? g2 : expm1f(g2);
    hv.w = (g3 > 0.f) ? g3 : expm1f(g3);
    *(float4*)&hout[(size_t)n * kHC + base] = hv;
}

// ---------------------------------------------------------------------------
// K6: agg[n] = mean over incoming edges of h[src], float4 per thread
// ---------------------------------------------------------------------------
__global__ __launch_bounds__(256) void agg_kernel(
    const float* __restrict__ h, const int* __restrict__ ssrc,
    const int* __restrict__ offsets, float* __restrict__ aggout)
{
    const int n = blockIdx.x;
    const int base = threadIdx.x * 4;
    float4 a = make_float4(0.f, 0.f, 0.f, 0.f);
    const int beg = offsets[n], end = offsets[n + 1];
    for (int e = beg; e < end; ++e) {
        const float4 hv = *(const float4*)&h[(size_t)ssrc[e] * kHC + base];
        a.x += hv.x; a.y += hv.y; a.z += hv.z; a.w += hv.w;
    }
    const float inv = 1.0f / fmaxf((float)(end - beg), 1.0f);
    a.x *= inv; a.y *= inv; a.z *= inv; a.w *= inv;
    *(float4*)&aggout[(size_t)n * kHC + base] = a;
}

// ---------------------------------------------------------------------------
// K8: in-place LayerNorm over last dim (1280). 320 threads x float4 per row.
// ---------------------------------------------------------------------------
__global__ __launch_bounds__(320) void ln_kernel(
    float* __restrict__ z, const float* __restrict__ gamma,
    const float* __restrict__ beta)
{
    const int r = blockIdx.x;
    const int t = threadIdx.x;
    const int wave = t >> 6, lane = t & 63;
    __shared__ float red[5];

    float4 v = *(const float4*)&z[(size_t)r * kESM + t * 4];
    float s = v.x + v.y + v.z + v.w;
#pragma unroll
    for (int o = 32; o >= 1; o >>= 1) s += __shfl_xor(s, o, 64);
    if (lane == 0) red[wave] = s;
    __syncthreads();
    s = red[0] + red[1] + red[2] + red[3] + red[4];
    const float mu = s * (1.0f / (float)kESM);

    float dx = v.x - mu, dy = v.y - mu, dz = v.z - mu, dw = v.w - mu;
    float q = dx * dx + dy * dy + dz * dz + dw * dw;
#pragma unroll
    for (int o = 32; o >= 1; o >>= 1) q += __shfl_xor(q, o, 64);
    __syncthreads();
    if (lane == 0) red[wave] = q;
    __syncthreads();
    q = red[0] + red[1] + red[2] + red[3] + red[4];
    const float rstd = rsqrtf(q * (1.0f / (float)kESM) + 1e-5f);

    const float4 g4 = *(const float4*)&gamma[t * 4];
    const float4 b4 = *(const float4*)&beta[t * 4];
    float4 o;
    o.x = dx * rstd * g4.x + b4.x;
    o.y = dy * rstd * g4.y + b4.y;
    o.z = dz * rstd * g4.z + b4.z;
    o.w = dw * rstd * g4.w + b4.w;
    *(float4*)&z[(size_t)r * kESM + t * 4] = o;
}

// ---------------------------------------------------------------------------
extern "C" void kernel_launch(void* const* d_in, const int* in_sizes, int n_in,
                              void* d_out, int out_size, void* d_ws, size_t ws_size,
                              hipStream_t stream)
{
    const float* x     = (const float*)d_in[0];
    const int*   ei    = (const int*)  d_in[1];
    const float* ew    = (const float*)d_in[2];
    const float* Wl    = (const float*)d_in[3];
    const float* bl    = (const float*)d_in[4];
    const float* Wr    = (const float*)d_in[5];
    const float* We    = (const float*)d_in[6];
    const float* att   = (const float*)d_in[7];
    const float* bgat  = (const float*)d_in[8];
    const float* Wsl   = (const float*)d_in[9];
    const float* bsl   = (const float*)d_in[10];
    const float* Wsr   = (const float*)d_in[11];
    const float* gamma = (const float*)d_in[12];
    const float* beta  = (const float*)d_in[13];
    const int* src = ei;
    const int* dst = ei + kE;

    char* ws = (char*)d_ws;
    size_t off = 0;
    auto alloc = [&](size_t bytes) -> void* {
        void* p = ws + off;
        off = (off + bytes + 255) & ~(size_t)255;
        return p;
    };
    int*   deg    = (int*)  alloc((size_t)kN * 4);
    int*   cnt    = (int*)  alloc((size_t)kN * 4);
    int*   offs   = (int*)  alloc((size_t)(kN + 1) * 4);
    float* loopat = (float*)alloc((size_t)kN * 4);
    int*   ssrc   = (int*)  alloc((size_t)kE * 4);
    float* sew    = (float*)alloc((size_t)kE * 4);
    float* bufA   = (float*)alloc((size_t)kN * kHC * 4);  // xl, later agg
    float* bufB   = (float*)alloc((size_t)kN * kHC * 4);  // xr, later h

    hipMemsetAsync(deg,    0, (size_t)kN * 4, stream);
    hipMemsetAsync(cnt,    0, (size_t)kN * 4, stream);
    hipMemsetAsync(loopat, 0, (size_t)kN * 4, stream);

    deg_kernel <<<(kE + 255) / 256, 256, 0, stream>>>(dst, ew, deg, loopat);
    scan_kernel<<<1, 256, 0, stream>>>(deg, loopat, offs);
    sort_kernel<<<(kE + 255) / 256, 256, 0, stream>>>(src, dst, ew, offs, cnt, ssrc, sew);

    dim3 g1(kHC / BN, (kN + BM - 1) / BM);
    gemm_kernel<<<g1, 256, 0, stream>>>(x, Wl, nullptr, nullptr, bl, nullptr,
                                        bufA, kN, kHC, kESM, 0);
    gemm_kernel<<<g1, 256, 0, stream>>>(x, Wr, nullptr, nullptr, nullptr, nullptr,
                                        bufB, kN, kHC, kESM, 0);

    gat_kernel<<<kN, 256, 0, stream>>>(bufA, bufB, ssrc, sew, offs, loopat,
                                       We, att, bgat, bufB);   // bufB: xr -> h (row-local)
    agg_kernel<<<kN, 256, 0, stream>>>(bufB, ssrc, offs, bufA); // bufA: xl -> agg

    dim3 g2(kESM / BN, (kN + BM - 1) / BM);
    gemm_kernel<<<g2, 256, 0, stream>>>(bufA, Wsl, bufB, Wsr, bsl, x,
                                        (float*)d_out, kN, kESM, kHC, 1);

    ln_kernel<<<kN, 320, 0, stream>>>((float*)d_out, gamma, beta);
}

// Round 3
// 1460.115 us; speedup vs baseline: 2.1847x; 2.1847x over previous
//
#include <hip/hip_runtime.h>
#include <hip/hip_bf16.h>
#include <math.h>

constexpr int kN   = 20000;
constexpr int kE   = 256000;
constexpr int kESM = 1280;
constexpr int kHC  = 1024;

typedef unsigned int  u32;
typedef unsigned short ushort_t;
typedef __bf16 bf16x8 __attribute__((ext_vector_type(8)));
typedef float  f32x4  __attribute__((ext_vector_type(4)));
typedef unsigned short u16x8 __attribute__((ext_vector_type(8)));
typedef unsigned short u16x4 __attribute__((ext_vector_type(4)));
typedef __attribute__((address_space(1))) const u32 gu32;
typedef __attribute__((address_space(3))) u32 lu32;

static __device__ __forceinline__ unsigned short f2bf_rne(float f) {
    u32 u = __float_as_uint(f);
    u32 r = (u + 0x7FFFu + ((u >> 16) & 1u)) >> 16;
    return (unsigned short)r;
}
static __device__ __forceinline__ float bf2f(unsigned short h) {
    return __uint_as_float(((u32)h) << 16);
}

// ---------------------------------------------------------------------------
// K1: degree + weighted-degree via atomics
// ---------------------------------------------------------------------------
__global__ __launch_bounds__(256) void deg_kernel(
    const int* __restrict__ dst, const float* __restrict__ ew,
    int* __restrict__ deg, float* __restrict__ wsum)
{
    int e = blockIdx.x * 256 + threadIdx.x;
    if (e < kE) {
        int d = dst[e];
        atomicAdd(&deg[d], 1);
        atomicAdd(&wsum[d], ew[e]);
    }
}

// ---------------------------------------------------------------------------
// K2: single-block exclusive scan of deg -> offsets; loop_attr = wsum/max(deg,1)
// ---------------------------------------------------------------------------
__global__ __launch_bounds__(256) void scan_kernel(
    const int* __restrict__ deg, float* __restrict__ loopat,
    int* __restrict__ offsets)
{
    __shared__ int s[256];
    int tid = threadIdx.x;
    int base = 0;
    if (tid == 0) offsets[0] = 0;
    for (int t0 = 0; t0 < kN; t0 += 256) {
        int i = t0 + tid;
        int d = (i < kN) ? deg[i] : 0;
        if (i < kN) {
            float w = loopat[i];
            loopat[i] = w / fmaxf((float)d, 1.0f);
        }
        s[tid] = d;
        int v = d;
        for (int off = 1; off < 256; off <<= 1) {
            __syncthreads();
            int add = (tid >= off) ? s[tid - off] : 0;
            __syncthreads();
            v += add;
            s[tid] = v;
        }
        __syncthreads();
        if (i < kN) offsets[i + 1] = base + v;
        base += s[255];
        __syncthreads();
    }
}

// ---------------------------------------------------------------------------
// K3: scatter edges into dst-sorted order
// ---------------------------------------------------------------------------
__global__ __launch_bounds__(256) void sort_kernel(
    const int* __restrict__ src, const int* __restrict__ dst,
    const float* __restrict__ ew, const int* __restrict__ offsets,
    int* __restrict__ cnt, int* __restrict__ ssrc, float* __restrict__ sew)
{
    int e = blockIdx.x * 256 + threadIdx.x;
    if (e < kE) {
        int d = dst[e];
        int p = offsets[d] + atomicAdd(&cnt[d], 1);
        ssrc[p] = src[e];
        sew[p]  = ew[e];
    }
}

// ===========================================================================
// FAST PATH: bf16x3 split MFMA GEMM with pre-packed operands.
// Packed tile layout per (mb/nb, kb): [hl(2)][g(4)][rc(128)][8] bf16 = 16 KB.
// Fragment read: lane l -> rc = base + (l&15), g = l>>4 -> one ds_read_b128.
// ===========================================================================

// pack A (fp32 [M][K], zero-pad rows >= M).  grid (NKB, MB), 512 thr.
__global__ __launch_bounds__(512) void pack_a_kernel(
    const float* __restrict__ A, int M, int K,
    int NKB, ushort_t* __restrict__ dst)
{
    const int kb = blockIdx.x, mb = blockIdx.y;
    const int tid = threadIdx.x;
    const int g = tid >> 7, r = tid & 127;
    const int row = mb * 128 + r;

    u16x8 hi, lo;
    if (row < M) {
        const float* src = A + (size_t)row * K + kb * 32 + g * 8;
        float4 v0 = *(const float4*)src;
        float4 v1 = *(const float4*)(src + 4);
        float vals[8] = {v0.x, v0.y, v0.z, v0.w, v1.x, v1.y, v1.z, v1.w};
#pragma unroll
        for (int j = 0; j < 8; ++j) {
            unsigned short h = f2bf_rne(vals[j]);
            hi[j] = h;
            lo[j] = f2bf_rne(vals[j] - bf2f(h));
        }
    } else {
#pragma unroll
        for (int j = 0; j < 8; ++j) { hi[j] = 0; lo[j] = 0; }
    }
    ushort_t* tb = dst + ((size_t)mb * NKB + kb) * 8192;
    *(u16x8*)&tb[0    + g * 1024 + r * 8] = hi;
    *(u16x8*)&tb[4096 + g * 1024 + r * 8] = lo;
}

// pack A2 = [agg(fp32) | h(bf16)] logical [M][2048].  grid (64, MB), 512 thr.
__global__ __launch_bounds__(512) void pack_a2_kernel(
    const float* __restrict__ agg, const ushort_t* __restrict__ hb,
    int M, ushort_t* __restrict__ dst)
{
    const int kb = blockIdx.x, mb = blockIdx.y;   // kb in [0,64)
    const int tid = threadIdx.x;
    const int g = tid >> 7, r = tid & 127;
    const int row = mb * 128 + r;

    u16x8 hi, lo;
    if (row < M) {
        if (kb < 32) {
            const float* src = agg + (size_t)row * 1024 + kb * 32 + g * 8;
            float4 v0 = *(const float4*)src;
            float4 v1 = *(const float4*)(src + 4);
            float vals[8] = {v0.x, v0.y, v0.z, v0.w, v1.x, v1.y, v1.z, v1.w};
#pragma unroll
            for (int j = 0; j < 8; ++j) {
                unsigned short h = f2bf_rne(vals[j]);
                hi[j] = h;
                lo[j] = f2bf_rne(vals[j] - bf2f(h));
            }
        } else {
            hi = *(const u16x8*)&hb[(size_t)row * 1024 + (kb - 32) * 32 + g * 8];
#pragma unroll
            for (int j = 0; j < 8; ++j) lo[j] = 0;
        }
    } else {
#pragma unroll
        for (int j = 0; j < 8; ++j) { hi[j] = 0; lo[j] = 0; }
    }
    ushort_t* tb = dst + ((size_t)mb * 64 + kb) * 8192;
    *(u16x8*)&tb[0    + g * 1024 + r * 8] = hi;
    *(u16x8*)&tb[4096 + g * 1024 + r * 8] = lo;
}

// pack B. mode 0 (col-split): B(k,n) = n<split ? B1[k][n] : B2[k][n-split]
//         mode 1 (row-split): B(k,n) = k<split ? B1[k][n] : B2[(k-split)][n]
// grid (NKB, N/128), 512 thr.
__global__ __launch_bounds__(512) void pack_b_kernel(
    const float* __restrict__ B1, const float* __restrict__ B2,
    int N, int split, int mode, ushort_t* __restrict__ dst)
{
    const int kb = blockIdx.x, nb = blockIdx.y;
    const int NKB = gridDim.x;
    const int tid = threadIdx.x;
    const int g = tid >> 7, c = tid & 127;
    const int n = nb * 128 + c;

    u16x8 hi, lo;
#pragma unroll
    for (int j = 0; j < 8; ++j) {
        int k = kb * 32 + g * 8 + j;
        float v;
        if (mode == 0) {
            v = (n < split) ? B1[(size_t)k * split + n]
                            : B2[(size_t)k * (N - split) + (n - split)];
        } else {
            v = (k < split) ? B1[(size_t)k * N + n]
                            : B2[(size_t)(k - split) * N + n];
        }
        unsigned short h = f2bf_rne(v);
        hi[j] = h;
        lo[j] = f2bf_rne(v - bf2f(h));
    }
    ushort_t* tb = dst + ((size_t)nb * NKB + kb) * 8192;
    *(u16x8*)&tb[0    + g * 1024 + c * 8] = hi;
    *(u16x8*)&tb[4096 + g * 1024 + c * 8] = lo;
}

// bf16x3 MFMA GEMM: C = epi(Ahi*Bhi + Ahi*Blo + Alo*Bhi).
// 128x128 tile, BK=32, 4 waves (2x2), 4x4 16x16x32 frags per wave.
__global__ __launch_bounds__(256) void gemm_mfma(
    const ushort_t* __restrict__ Ap, const ushort_t* __restrict__ Bp,
    const float* __restrict__ bias, int biasN,
    const float* __restrict__ resid, float* __restrict__ C,
    int M, int N, int NKB, int do_relu)
{
    __shared__ ushort_t sb[16384];   // 32KB: A tile [0..8191], B tile [8192..]
    const int tid  = threadIdx.x;
    const int wid  = tid >> 6;
    const int lane = tid & 63;
    const int l15 = lane & 15, l4 = lane >> 4;
    const int mb = blockIdx.y, nb = blockIdx.x;
    const int wr = wid >> 1, wc = wid & 1;

    f32x4 acc[4][4];
#pragma unroll
    for (int i = 0; i < 4; ++i)
#pragma unroll
        for (int j = 0; j < 4; ++j) acc[i][j] = (f32x4){0.f, 0.f, 0.f, 0.f};

    const char* at = (const char*)(Ap + (size_t)mb * NKB * 8192);
    const char* bt = (const char*)(Bp + (size_t)nb * NKB * 8192);

    for (int kb = 0; kb < NKB; ++kb) {
        const char* atk = at + (size_t)kb * 16384;
        const char* btk = bt + (size_t)kb * 16384;
#pragma unroll
        for (int c = 0; c < 4; ++c) {
            __builtin_amdgcn_global_load_lds(
                (gu32*)(atk + c * 4096 + tid * 16),
                (lu32*)&sb[c * 2048 + wid * 512], 16, 0, 0);
            __builtin_amdgcn_global_load_lds(
                (gu32*)(btk + c * 4096 + tid * 16),
                (lu32*)&sb[8192 + c * 2048 + wid * 512], 16, 0, 0);
        }
        __syncthreads();

        bf16x8 af[2][4], bv[2][4];
#pragma unroll
        for (int hl = 0; hl < 2; ++hl)
#pragma unroll
            for (int m = 0; m < 4; ++m)
                af[hl][m] = *(const bf16x8*)&sb[hl * 4096 + l4 * 1024 + (wr * 64 + m * 16 + l15) * 8];
#pragma unroll
        for (int hl = 0; hl < 2; ++hl)
#pragma unroll
            for (int n = 0; n < 4; ++n)
                bv[hl][n] = *(const bf16x8*)&sb[8192 + hl * 4096 + l4 * 1024 + (wc * 64 + n * 16 + l15) * 8];

#pragma unroll
        for (int m = 0; m < 4; ++m)
#pragma unroll
            for (int n = 0; n < 4; ++n) {
                acc[m][n] = __builtin_amdgcn_mfma_f32_16x16x32_bf16(af[0][m], bv[0][n], acc[m][n], 0, 0, 0);
                acc[m][n] = __builtin_amdgcn_mfma_f32_16x16x32_bf16(af[0][m], bv[1][n], acc[m][n], 0, 0, 0);
                acc[m][n] = __builtin_amdgcn_mfma_f32_16x16x32_bf16(af[1][m], bv[0][n], acc[m][n], 0, 0, 0);
            }
        __syncthreads();
    }

    const int row_w = mb * 128 + wr * 64;
    const int col_w = nb * 128 + wc * 64;
#pragma unroll
    for (int m = 0; m < 4; ++m) {
#pragma unroll
        for (int n = 0; n < 4; ++n) {
            const int col = col_w + n * 16 + l15;
#pragma unroll
            for (int j = 0; j < 4; ++j) {
                const int row = row_w + m * 16 + l4 * 4 + j;
                if (row < M) {
                    float v = acc[m][n][j];
                    if (bias && col < biasN) v += bias[col];
                    if (do_relu) v = fmaxf(v, 0.f);
                    if (resid) v += resid[(size_t)row * N + col];
                    C[(size_t)row * N + col] = v;
                }
            }
        }
    }
}

// fused GAT (fast path): xlr fp32 [N][2048] (xl cols 0..1023, xr 1024..2047),
// h out bf16 [N][1024].
__global__ __launch_bounds__(256) void gat2_kernel(
    const float* __restrict__ xlr, const int* __restrict__ ssrc,
    const float* __restrict__ sew, const int* __restrict__ offsets,
    const float* __restrict__ loopat, const float* __restrict__ We,
    const float* __restrict__ att, const float* __restrict__ bgat,
    ushort_t* __restrict__ hout)
{
    const int n = blockIdx.x;
    const int base = threadIdx.x * 4;

    const float4 xr4 = *(const float4*)&xlr[(size_t)n * 2048 + 1024 + base];
    const float4 We4 = *(const float4*)&We[base];
    const float4 at4 = *(const float4*)&att[base];

    float M = -INFINITY, D = 0.f;
    float4 acc = make_float4(0.f, 0.f, 0.f, 0.f);

    const int beg = offsets[n], end = offsets[n + 1];
    for (int e = beg; e <= end; ++e) {
        int s; float w;
        if (e < end) { s = ssrc[e]; w = sew[e]; }
        else         { s = n;       w = loopat[n]; }

        const float4 xls = *(const float4*)&xlr[(size_t)s * 2048 + base];
        float m0 = xls.x + xr4.x + w * We4.x;
        float m1 = xls.y + xr4.y + w * We4.y;
        float m2 = xls.z + xr4.z + w * We4.z;
        float m3 = xls.w + xr4.w + w * We4.w;
        m0 = (m0 >= 0.f) ? m0 : 0.2f * m0;
        m1 = (m1 >= 0.f) ? m1 : 0.2f * m1;
        m2 = (m2 >= 0.f) ? m2 : 0.2f * m2;
        m3 = (m3 >= 0.f) ? m3 : 0.2f * m3;
        float p = m0 * at4.x + m1 * at4.y + m2 * at4.z + m3 * at4.w;
#pragma unroll
        for (int o = 32; o >= 1; o >>= 1) p += __shfl_xor(p, o, 64);

        float newM  = fmaxf(M, p);
        float scale = __expf(M - newM);
        float wexp  = __expf(p - newM);
        D     = D * scale + wexp;
        acc.x = acc.x * scale + wexp * xls.x;
        acc.y = acc.y * scale + wexp * xls.y;
        acc.z = acc.z * scale + wexp * xls.z;
        acc.w = acc.w * scale + wexp * xls.w;
        M = newM;
    }

    const float inv = 1.0f / (D + 1e-16f);
    float g0 = acc.x * inv + bgat[base + 0];
    float g1 = acc.y * inv + bgat[base + 1];
    float g2 = acc.z * inv + bgat[base + 2];
    float g3 = acc.w * inv + bgat[base + 3];
    u16x4 hv;
    hv[0] = f2bf_rne((g0 > 0.f) ? g0 : expm1f(g0));
    hv[1] = f2bf_rne((g1 > 0.f) ? g1 : expm1f(g1));
    hv[2] = f2bf_rne((g2 > 0.f) ? g2 : expm1f(g2));
    hv[3] = f2bf_rne((g3 > 0.f) ? g3 : expm1f(g3));
    *(u16x4*)&hout[(size_t)n * 1024 + base] = hv;
}

// agg (fast path): mean of bf16 h[src] rows -> fp32 agg
__global__ __launch_bounds__(256) void agg2_kernel(
    const ushort_t* __restrict__ hb, const int* __restrict__ ssrc,
    const int* __restrict__ offsets, float* __restrict__ aggout)
{
    const int n = blockIdx.x;
    const int base = threadIdx.x * 4;
    float4 a = make_float4(0.f, 0.f, 0.f, 0.f);
    const int beg = offsets[n], end = offsets[n + 1];
    for (int e = beg; e < end; ++e) {
        const u16x4 hv = *(const u16x4*)&hb[(size_t)ssrc[e] * 1024 + base];
        a.x += bf2f(hv[0]); a.y += bf2f(hv[1]);
        a.z += bf2f(hv[2]); a.w += bf2f(hv[3]);
    }
    const float inv = 1.0f / fmaxf((float)(end - beg), 1.0f);
    a.x *= inv; a.y *= inv; a.z *= inv; a.w *= inv;
    *(float4*)&aggout[(size_t)n * 1024 + base] = a;
}

// ---------------------------------------------------------------------------
// LayerNorm over last dim (1280), in-place. 320 threads x float4 per row.
// ---------------------------------------------------------------------------
__global__ __launch_bounds__(320) void ln_kernel(
    float* __restrict__ z, const float* __restrict__ gamma,
    const float* __restrict__ beta)
{
    const int r = blockIdx.x;
    const int t = threadIdx.x;
    const int wave = t >> 6, lane = t & 63;
    __shared__ float red[5];

    float4 v = *(const float4*)&z[(size_t)r * kESM + t * 4];
    float s = v.x + v.y + v.z + v.w;
#pragma unroll
    for (int o = 32; o >= 1; o >>= 1) s += __shfl_xor(s, o, 64);
    if (lane == 0) red[wave] = s;
    __syncthreads();
    s = red[0] + red[1] + red[2] + red[3] + red[4];
    const float mu = s * (1.0f / (float)kESM);

    float dx = v.x - mu, dy = v.y - mu, dz = v.z - mu, dw = v.w - mu;
    float q = dx * dx + dy * dy + dz * dz + dw * dw;
#pragma unroll
    for (int o = 32; o >= 1; o >>= 1) q += __shfl_xor(q, o, 64);
    __syncthreads();
    if (lane == 0) red[wave] = q;
    __syncthreads();
    q = red[0] + red[1] + red[2] + red[3] + red[4];
    const float rstd = rsqrtf(q * (1.0f / (float)kESM) + 1e-5f);

    const float4 g4 = *(const float4*)&gamma[t * 4];
    const float4 b4 = *(const float4*)&beta[t * 4];
    float4 o;
    o.x = dx * rstd * g4.x + b4.x;
    o.y = dy * rstd * g4.y + b4.y;
    o.z = dz * rstd * g4.z + b4.z;
    o.w = dw * rstd * g4.w + b4.w;
    *(float4*)&z[(size_t)r * kESM + t * 4] = o;
}

// ===========================================================================
// FALLBACK PATH (round-2, known-pass): fp32 vector GEMM + fp32 gat/agg
// ===========================================================================
#define BM 128
#define BN 128
#define BK 16

__global__ __launch_bounds__(256) void gemm_kernel(
    const float* __restrict__ A,  const float* __restrict__ B,
    const float* __restrict__ A2, const float* __restrict__ B2,
    const float* __restrict__ bias, const float* __restrict__ resid,
    float* __restrict__ C, int M, int N, int K, int do_relu)
{
    __shared__ float As[BK][BM];
    __shared__ float Bs[BK][BN];

    const int tid = threadIdx.x;
    const int bm = blockIdx.y, bn = blockIdx.x;
    const int row0 = bm * BM, col0 = bn * BN;
    const int tx = tid & 15, ty = tid >> 4;

    float acc[8][8];
#pragma unroll
    for (int i = 0; i < 8; ++i)
#pragma unroll
        for (int j = 0; j < 8; ++j) acc[i][j] = 0.0f;

    const int arow  = tid >> 1;
    const int akoff = (tid & 1) * 8;
    const int bkr   = tid >> 4;
    const int bcol  = (tid & 15) * 8;

    for (int pair = 0; pair < 2; ++pair) {
        const float* Ap = pair ? A2 : A;
        const float* Bp = pair ? B2 : B;
        if (!Ap) break;
        for (int k0 = 0; k0 < K; k0 += BK) {
            float4 a0 = make_float4(0.f, 0.f, 0.f, 0.f);
            float4 a1 = a0;
            int gr = row0 + arow;
            if (gr < M) {
                const float* aptr = Ap + (size_t)gr * K + k0 + akoff;
                a0 = *(const float4*)aptr;
                a1 = *(const float4*)(aptr + 4);
            }
            const float* bptr = Bp + (size_t)(k0 + bkr) * N + col0 + bcol;
            float4 b0 = *(const float4*)bptr;
            float4 b1 = *(const float4*)(bptr + 4);

            __syncthreads();
            As[akoff + 0][arow] = a0.x;
            As[akoff + 1][arow] = a0.y;
            As[akoff + 2][arow] = a0.z;
            As[akoff + 3][arow] = a0.w;
            As[akoff + 4][arow] = a1.x;
            As[akoff + 5][arow] = a1.y;
            As[akoff + 6][arow] = a1.z;
            As[akoff + 7][arow] = a1.w;
            *(float4*)&Bs[bkr][bcol]     = b0;
            *(float4*)&Bs[bkr][bcol + 4] = b1;
            __syncthreads();

#pragma unroll
            for (int kk = 0; kk < BK; ++kk) {
                float4 a0r = *(const float4*)&As[kk][ty * 8];
                float4 a1r = *(const float4*)&As[kk][ty * 8 + 4];
                float4 b0r = *(const float4*)&Bs[kk][tx * 4];
                float4 b1r = *(const float4*)&Bs[kk][64 + tx * 4];
                float ar[8] = {a0r.x, a0r.y, a0r.z, a0r.w, a1r.x, a1r.y, a1r.z, a1r.w};
                float br[8] = {b0r.x, b0r.y, b0r.z, b0r.w, b1r.x, b1r.y, b1r.z, b1r.w};
#pragma unroll
                for (int i = 0; i < 8; ++i)
#pragma unroll
                    for (int j = 0; j < 8; ++j)
                        acc[i][j] = fmaf(ar[i], br[j], acc[i][j]);
            }
        }
    }

#pragma unroll
    for (int i = 0; i < 8; ++i) {
        int gr = row0 + ty * 8 + i;
        if (gr >= M) break;
#pragma unroll
        for (int half = 0; half < 2; ++half) {
            int gc = col0 + half * 64 + tx * 4;
            float4 out;
            float* o = &out.x;
            const float* rrow = resid ? (resid + (size_t)gr * N + gc) : nullptr;
#pragma unroll
            for (int j = 0; j < 4; ++j) {
                float v = acc[i][half * 4 + j];
                if (bias) v += bias[gc + j];
                if (do_relu) v = fmaxf(v, 0.0f);
                if (rrow) v += rrow[j];
                o[j] = v;
            }
            *(float4*)&C[(size_t)gr * N + gc] = out;
        }
    }
}

__global__ __launch_bounds__(256) void gat_kernel(
    const float* __restrict__ xl, const float* __restrict__ xr,
    const int* __restrict__ ssrc, const float* __restrict__ sew,
    const int* __restrict__ offsets, const float* __restrict__ loopat,
    const float* __restrict__ We, const float* __restrict__ att,
    const float* __restrict__ bgat, float* __restrict__ hout)
{
    const int n = blockIdx.x;
    const int base = threadIdx.x * 4;

    const float4 xr4 = *(const float4*)&xr[(size_t)n * kHC + base];
    const float4 We4 = *(const float4*)&We[base];
    const float4 at4 = *(const float4*)&att[base];

    float M = -INFINITY, D = 0.f;
    float4 acc = make_float4(0.f, 0.f, 0.f, 0.f);

    const int beg = offsets[n], end = offsets[n + 1];
    for (int e = beg; e <= end; ++e) {
        int s; float w;
        if (e < end) { s = ssrc[e]; w = sew[e]; }
        else         { s = n;       w = loopat[n]; }

        const float4 xls = *(const float4*)&xl[(size_t)s * kHC + base];
        float m0 = xls.x + xr4.x + w * We4.x;
        float m1 = xls.y + xr4.y + w * We4.y;
        float m2 = xls.z + xr4.z + w * We4.z;
        float m3 = xls.w + xr4.w + w * We4.w;
        m0 = (m0 >= 0.f) ? m0 : 0.2f * m0;
        m1 = (m1 >= 0.f) ? m1 : 0.2f * m1;
        m2 = (m2 >= 0.f) ? m2 : 0.2f * m2;
        m3 = (m3 >= 0.f) ? m3 : 0.2f * m3;
        float p = m0 * at4.x + m1 * at4.y + m2 * at4.z + m3 * at4.w;
#pragma unroll
        for (int o = 32; o >= 1; o >>= 1) p += __shfl_xor(p, o, 64);

        float newM  = fmaxf(M, p);
        float scale = __expf(M - newM);
        float wexp  = __expf(p - newM);
        D     = D * scale + wexp;
        acc.x = acc.x * scale + wexp * xls.x;
        acc.y = acc.y * scale + wexp * xls.y;
        acc.z = acc.z * scale + wexp * xls.z;
        acc.w = acc.w * scale + wexp * xls.w;
        M = newM;
    }

    const float inv = 1.0f / (D + 1e-16f);
    float g0 = acc.x * inv + bgat[base + 0];
    float g1 = acc.y * inv + bgat[base + 1];
    float g2 = acc.z * inv + bgat[base + 2];
    float g3 = acc.w * inv + bgat[base + 3];
    float4 hv;
    hv.x = (g0 > 0.f) ? g0 : expm1f(g0);
    hv.y = (g1 > 0.f) ? g1 : expm1f(g1);
    hv.z = (g2 > 0.f) ? g2 : expm1f(g2);
    hv.w = (g3 > 0.f) ? g3 : expm1f(g3);
    *(float4*)&hout[(size_t)n * kHC + base] = hv;
}

__global__ __launch_bounds__(256) void agg_kernel(
    const float* __restrict__ h, const int* __restrict__ ssrc,
    const int* __restrict__ offsets, float* __restrict__ aggout)
{
    const int n = blockIdx.x;
    const int base = threadIdx.x * 4;
    float4 a = make_float4(0.f, 0.f, 0.f, 0.f);
    const int beg = offsets[n], end = offsets[n + 1];
    for (int e = beg; e < end; ++e) {
        const float4 hv = *(const float4*)&h[(size_t)ssrc[e] * kHC + base];
        a.x += hv.x; a.y += hv.y; a.z += hv.z; a.w += hv.w;
    }
    const float inv = 1.0f / fmaxf((float)(end - beg), 1.0f);
    a.x *= inv; a.y *= inv; a.z *= inv; a.w *= inv;
    *(float4*)&aggout[(size_t)n * kHC + base] = a;
}

// ---------------------------------------------------------------------------
extern "C" void kernel_launch(void* const* d_in, const int* in_sizes, int n_in,
                              void* d_out, int out_size, void* d_ws, size_t ws_size,
                              hipStream_t stream)
{
    const float* x     = (const float*)d_in[0];
    const int*   ei    = (const int*)  d_in[1];
    const float* ew    = (const float*)d_in[2];
    const float* Wl    = (const float*)d_in[3];
    const float* bl    = (const float*)d_in[4];
    const float* Wr    = (const float*)d_in[5];
    const float* We    = (const float*)d_in[6];
    const float* att   = (const float*)d_in[7];
    const float* bgat  = (const float*)d_in[8];
    const float* Wsl   = (const float*)d_in[9];
    const float* bsl   = (const float*)d_in[10];
    const float* Wsr   = (const float*)d_in[11];
    const float* gamma = (const float*)d_in[12];
    const float* beta  = (const float*)d_in[13];
    const int* src = ei;
    const int* dst = ei + kE;
    char* ws = (char*)d_ws;

    // fast-path layout (bytes)
    const size_t SZ_XPACK = (size_t)157 * 40 * 16384;        // 102,891,520
    const size_t SZ_XLR   = (size_t)kN * 2048 * 4;           // 163,840,000
    const size_t SZ_HBUF  = (size_t)kN * 1024 * 2;           //  40,960,000
    const size_t SZ_B1    = (size_t)16 * 40 * 16384;         //  10,485,760
    const size_t SZ_B2    = (size_t)10 * 64 * 16384;         //  10,485,760
    const size_t OFF_XLR  = SZ_XPACK;
    const size_t OFF_HBUF = OFF_XLR + SZ_XLR;
    const size_t OFF_B1   = OFF_HBUF + SZ_HBUF;
    const size_t OFF_B2   = OFF_B1 + SZ_B1;
    size_t off = OFF_B2 + SZ_B2;
    auto salloc = [&](size_t bytes) -> void* {
        void* p = ws + off;
        off = (off + bytes + 255) & ~(size_t)255;
        return p;
    };
    int*   deg    = (int*)  salloc((size_t)kN * 4);
    int*   cnt    = (int*)  salloc((size_t)kN * 4);
    int*   offs   = (int*)  salloc((size_t)(kN + 1) * 4);
    float* loopat = (float*)salloc((size_t)kN * 4);
    int*   ssrc   = (int*)  salloc((size_t)kE * 4);
    float* sew    = (float*)salloc((size_t)kE * 4);
    const size_t FAST_TOTAL = off;

    if (ws_size >= FAST_TOTAL) {
        // ------------------ FAST PATH ------------------
        ushort_t* xpack = (ushort_t*)(ws);
        float*    xlr   = (float*)   (ws + OFF_XLR);
        ushort_t* hbuf  = (ushort_t*)(ws + OFF_HBUF);
        ushort_t* b1p   = (ushort_t*)(ws + OFF_B1);
        ushort_t* b2p   = (ushort_t*)(ws + OFF_B2);
        // aliases (lifetimes verified): agg over tail of dead xlr; apack over dead xpack+xlr head
        float*    aggb  = (float*)   (ws + OFF_HBUF - (size_t)kN * 1024 * 4);  // 184,811,520
        ushort_t* apack = (ushort_t*)(ws);                                      // needs 164.6MB < 184.8MB

        hipMemsetAsync(deg,    0, (size_t)kN * 4, stream);
        hipMemsetAsync(cnt,    0, (size_t)kN * 4, stream);
        hipMemsetAsync(loopat, 0, (size_t)kN * 4, stream);

        deg_kernel <<<(kE + 255) / 256, 256, 0, stream>>>(dst, ew, deg, loopat);
        scan_kernel<<<1, 256, 0, stream>>>(deg, loopat, offs);
        sort_kernel<<<(kE + 255) / 256, 256, 0, stream>>>(src, dst, ew, offs, cnt, ssrc, sew);

        pack_a_kernel<<<dim3(40, 157), 512, 0, stream>>>(x, kN, kESM, 40, xpack);
        pack_b_kernel<<<dim3(40, 16), 512, 0, stream>>>(Wl, Wr, 2048, 1024, 0, b1p);
        pack_b_kernel<<<dim3(64, 10), 512, 0, stream>>>(Wsl, Wsr, 1280, 1024, 1, b2p);

        gemm_mfma<<<dim3(16, 157), 256, 0, stream>>>(xpack, b1p, bl, 1024,
                                                     nullptr, xlr, kN, 2048, 40, 0);

        gat2_kernel<<<kN, 256, 0, stream>>>(xlr, ssrc, sew, offs, loopat,
                                            We, att, bgat, hbuf);
        agg2_kernel<<<kN, 256, 0, stream>>>(hbuf, ssrc, offs, aggb);

        pack_a2_kernel<<<dim3(64, 157), 512, 0, stream>>>(aggb, hbuf, kN, apack);

        gemm_mfma<<<dim3(10, 157), 256, 0, stream>>>(apack, b2p, bsl, 1280,
                                                     x, (float*)d_out, kN, 1280, 64, 1);

        ln_kernel<<<kN, 320, 0, stream>>>((float*)d_out, gamma, beta);
    } else {
        // ------------------ FALLBACK (round-2) ------------------
        size_t foff = 0;
        auto falloc = [&](size_t bytes) -> void* {
            void* p = ws + foff;
            foff = (foff + bytes + 255) & ~(size_t)255;
            return p;
        };
        int*   fdeg    = (int*)  falloc((size_t)kN * 4);
        int*   fcnt    = (int*)  falloc((size_t)kN * 4);
        int*   foffs   = (int*)  falloc((size_t)(kN + 1) * 4);
        float* floopat = (float*)falloc((size_t)kN * 4);
        int*   fssrc   = (int*)  falloc((size_t)kE * 4);
        float* fsew    = (float*)falloc((size_t)kE * 4);
        float* bufA    = (float*)falloc((size_t)kN * kHC * 4);
        float* bufB    = (float*)falloc((size_t)kN * kHC * 4);

        hipMemsetAsync(fdeg,    0, (size_t)kN * 4, stream);
        hipMemsetAsync(fcnt,    0, (size_t)kN * 4, stream);
        hipMemsetAsync(floopat, 0, (size_t)kN * 4, stream);

        deg_kernel <<<(kE + 255) / 256, 256, 0, stream>>>(dst, ew, fdeg, floopat);
        scan_kernel<<<1, 256, 0, stream>>>(fdeg, floopat, foffs);
        sort_kernel<<<(kE + 255) / 256, 256, 0, stream>>>(src, dst, ew, foffs, fcnt, fssrc, fsew);

        dim3 g1(kHC / BN, (kN + BM - 1) / BM);
        gemm_kernel<<<g1, 256, 0, stream>>>(x, Wl, nullptr, nullptr, bl, nullptr,
                                            bufA, kN, kHC, kESM, 0);
        gemm_kernel<<<g1, 256, 0, stream>>>(x, Wr, nullptr, nullptr, nullptr, nullptr,
                                            bufB, kN, kHC, kESM, 0);

        gat_kernel<<<kN, 256, 0, stream>>>(bufA, bufB, fssrc, fsew, foffs, floopat,
                                           We, att, bgat, bufB);
        agg_kernel<<<kN, 256, 0, stream>>>(bufB, fssrc, foffs, bufA);

        dim3 g2(kESM / BN, (kN + BM - 1) / BM);
        gemm_kernel<<<g2, 256, 0, stream>>>(bufA, Wsl, bufB, Wsr, bsl, x,
                                            (float*)d_out, kN, kESM, kHC, 1);

        ln_kernel<<<kN, 320, 0, stream>>>((float*)d_out, gamma, beta);
    }
}

// Round 5
// 1405.395 us; speedup vs baseline: 2.2698x; 1.0389x over previous
//
#include <hip/hip_runtime.h>
#include <hip/hip_bf16.h>
#include <math.h>

constexpr int kN   = 20000;
constexpr int kE   = 256000;
constexpr int kESM = 1280;
constexpr int kHC  = 1024;

typedef unsigned int  u32;
typedef unsigned short ushort_t;
typedef __bf16 bf16x8 __attribute__((ext_vector_type(8)));
typedef float  f32x4  __attribute__((ext_vector_type(4)));
typedef unsigned short u16x8 __attribute__((ext_vector_type(8)));
typedef unsigned short u16x4 __attribute__((ext_vector_type(4)));
typedef __attribute__((address_space(1))) const u32 gu32;
typedef __attribute__((address_space(3))) u32 lu32;

static __device__ __forceinline__ unsigned short f2bf_rne(float f) {
    u32 u = __float_as_uint(f);
    u32 r = (u + 0x7FFFu + ((u >> 16) & 1u)) >> 16;
    return (unsigned short)r;
}
static __device__ __forceinline__ float bf2f(unsigned short h) {
    return __uint_as_float(((u32)h) << 16);
}

// ---------------------------------------------------------------------------
// K1: degree + weighted-degree via atomics
// ---------------------------------------------------------------------------
__global__ __launch_bounds__(256) void deg_kernel(
    const int* __restrict__ dst, const float* __restrict__ ew,
    int* __restrict__ deg, float* __restrict__ wsum)
{
    int e = blockIdx.x * 256 + threadIdx.x;
    if (e < kE) {
        int d = dst[e];
        atomicAdd(&deg[d], 1);
        atomicAdd(&wsum[d], ew[e]);
    }
}

// ---------------------------------------------------------------------------
// K2: single-block exclusive scan of deg -> offsets; loop_attr = wsum/max(deg,1)
// ---------------------------------------------------------------------------
__global__ __launch_bounds__(256) void scan_kernel(
    const int* __restrict__ deg, float* __restrict__ loopat,
    int* __restrict__ offsets)
{
    __shared__ int s[256];
    int tid = threadIdx.x;
    int base = 0;
    if (tid == 0) offsets[0] = 0;
    for (int t0 = 0; t0 < kN; t0 += 256) {
        int i = t0 + tid;
        int d = (i < kN) ? deg[i] : 0;
        if (i < kN) {
            float w = loopat[i];
            loopat[i] = w / fmaxf((float)d, 1.0f);
        }
        s[tid] = d;
        int v = d;
        for (int off = 1; off < 256; off <<= 1) {
            __syncthreads();
            int add = (tid >= off) ? s[tid - off] : 0;
            __syncthreads();
            v += add;
            s[tid] = v;
        }
        __syncthreads();
        if (i < kN) offsets[i + 1] = base + v;
        base += s[255];
        __syncthreads();
    }
}

// ---------------------------------------------------------------------------
// K3: scatter edges into dst-sorted order
// ---------------------------------------------------------------------------
__global__ __launch_bounds__(256) void sort_kernel(
    const int* __restrict__ src, const int* __restrict__ dst,
    const float* __restrict__ ew, const int* __restrict__ offsets,
    int* __restrict__ cnt, int* __restrict__ ssrc, float* __restrict__ sew)
{
    int e = blockIdx.x * 256 + threadIdx.x;
    if (e < kE) {
        int d = dst[e];
        int p = offsets[d] + atomicAdd(&cnt[d], 1);
        ssrc[p] = src[e];
        sew[p]  = ew[e];
    }
}

// ===========================================================================
// FAST PATH: bf16x3 split MFMA GEMM with pre-packed operands.
// Packed tile layout per (mb/nb, kb): [hl(2)][g(4)][rc(128)][8] bf16 = 16 KB.
// Fragment read: lane l -> rc = base + (l&15), g = l>>4 -> one ds_read_b128.
// ===========================================================================

// pack A (fp32 [M][K], zero-pad rows >= M).  grid (NKB, MB), 512 thr.
__global__ __launch_bounds__(512) void pack_a_kernel(
    const float* __restrict__ A, int M, int K,
    int NKB, ushort_t* __restrict__ dst)
{
    const int kb = blockIdx.x, mb = blockIdx.y;
    const int tid = threadIdx.x;
    const int g = tid >> 7, r = tid & 127;
    const int row = mb * 128 + r;

    u16x8 hi, lo;
    if (row < M) {
        const float* src = A + (size_t)row * K + kb * 32 + g * 8;
        float4 v0 = *(const float4*)src;
        float4 v1 = *(const float4*)(src + 4);
        float vals[8] = {v0.x, v0.y, v0.z, v0.w, v1.x, v1.y, v1.z, v1.w};
#pragma unroll
        for (int j = 0; j < 8; ++j) {
            unsigned short h = f2bf_rne(vals[j]);
            hi[j] = h;
            lo[j] = f2bf_rne(vals[j] - bf2f(h));
        }
    } else {
#pragma unroll
        for (int j = 0; j < 8; ++j) { hi[j] = 0; lo[j] = 0; }
    }
    ushort_t* tb = dst + ((size_t)mb * NKB + kb) * 8192;
    *(u16x8*)&tb[0    + g * 1024 + r * 8] = hi;
    *(u16x8*)&tb[4096 + g * 1024 + r * 8] = lo;
}

// pack A2 = [agg(fp32) | h(bf16)] logical [M][2048].  grid (64, MB), 512 thr.
// For kb >= 32 (the h half) A-lo is exactly zero -> NOT written; gemm_mfma
// is told via nkb_full to never read it.
__global__ __launch_bounds__(512) void pack_a2_kernel(
    const float* __restrict__ agg, const ushort_t* __restrict__ hb,
    int M, ushort_t* __restrict__ dst)
{
    const int kb = blockIdx.x, mb = blockIdx.y;   // kb in [0,64)
    const int tid = threadIdx.x;
    const int g = tid >> 7, r = tid & 127;
    const int row = mb * 128 + r;
    ushort_t* tb = dst + ((size_t)mb * 64 + kb) * 8192;

    if (kb < 32) {
        u16x8 hi, lo;
        if (row < M) {
            const float* src = agg + (size_t)row * 1024 + kb * 32 + g * 8;
            float4 v0 = *(const float4*)src;
            float4 v1 = *(const float4*)(src + 4);
            float vals[8] = {v0.x, v0.y, v0.z, v0.w, v1.x, v1.y, v1.z, v1.w};
#pragma unroll
            for (int j = 0; j < 8; ++j) {
                unsigned short h = f2bf_rne(vals[j]);
                hi[j] = h;
                lo[j] = f2bf_rne(vals[j] - bf2f(h));
            }
        } else {
#pragma unroll
            for (int j = 0; j < 8; ++j) { hi[j] = 0; lo[j] = 0; }
        }
        *(u16x8*)&tb[0    + g * 1024 + r * 8] = hi;
        *(u16x8*)&tb[4096 + g * 1024 + r * 8] = lo;
    } else {
        u16x8 hi;
        if (row < M) {
            hi = *(const u16x8*)&hb[(size_t)row * 1024 + (kb - 32) * 32 + g * 8];
        } else {
#pragma unroll
            for (int j = 0; j < 8; ++j) hi[j] = 0;
        }
        *(u16x8*)&tb[0 + g * 1024 + r * 8] = hi;   // lo plane left unwritten (unread)
    }
}

// pack B. mode 0 (col-split): B(k,n) = n<split ? B1[k][n] : B2[k][n-split]
//         mode 1 (row-split): B(k,n) = k<split ? B1[k][n] : B2[(k-split)][n]
// grid (NKB, N/128), 512 thr.
__global__ __launch_bounds__(512) void pack_b_kernel(
    const float* __restrict__ B1, const float* __restrict__ B2,
    int N, int split, int mode, ushort_t* __restrict__ dst)
{
    const int kb = blockIdx.x, nb = blockIdx.y;
    const int NKB = gridDim.x;
    const int tid = threadIdx.x;
    const int g = tid >> 7, c = tid & 127;
    const int n = nb * 128 + c;

    u16x8 hi, lo;
#pragma unroll
    for (int j = 0; j < 8; ++j) {
        int k = kb * 32 + g * 8 + j;
        float v;
        if (mode == 0) {
            v = (n < split) ? B1[(size_t)k * split + n]
                            : B2[(size_t)k * (N - split) + (n - split)];
        } else {
            v = (k < split) ? B1[(size_t)k * N + n]
                            : B2[(size_t)(k - split) * N + n];
        }
        unsigned short h = f2bf_rne(v);
        hi[j] = h;
        lo[j] = f2bf_rne(v - bf2f(h));
    }
    ushort_t* tb = dst + ((size_t)nb * NKB + kb) * 8192;
    *(u16x8*)&tb[0    + g * 1024 + c * 8] = hi;
    *(u16x8*)&tb[4096 + g * 1024 + c * 8] = lo;
}

// bf16x3 MFMA GEMM: C = epi(Ahi*Bhi + Ahi*Blo + Alo*Bhi).
// 128x128 tile, BK=32, 4 waves (2x2), 4x4 16x16x32 frags per wave.
// For kb >= nkb_full, A-lo is known-zero: load hi only, 2 products.
// XCD-aware bijective block swizzle (m204) for A-panel L2 locality.
__global__ __launch_bounds__(256) void gemm_mfma(
    const ushort_t* __restrict__ Ap, const ushort_t* __restrict__ Bp,
    const float* __restrict__ bias, int biasN,
    const float* __restrict__ resid, float* __restrict__ C,
    int M, int N, int NKB, int nkb_full, int do_relu)
{
    __shared__ ushort_t sb[16384];   // 32KB: A tile [0..8191], B tile [8192..]
    const int tid  = threadIdx.x;
    const int wid  = tid >> 6;
    const int lane = tid & 63;
    const int l15 = lane & 15, l4 = lane >> 4;

    // bijective XCD swizzle: same-XCD blocks get consecutive (mb,nb)
    const int nwg = gridDim.x * gridDim.y;
    const int lin = blockIdx.y * gridDim.x + blockIdx.x;
    const int q = nwg >> 3, r = nwg & 7;
    const int xcd = lin & 7, pos = lin >> 3;
    const int swz = (xcd < r ? xcd * (q + 1) : r * (q + 1) + (xcd - r) * q) + pos;
    const int mb = swz / gridDim.x, nb = swz % gridDim.x;
    const int wr = wid >> 1, wc = wid & 1;

    f32x4 acc[4][4];
#pragma unroll
    for (int i = 0; i < 4; ++i)
#pragma unroll
        for (int j = 0; j < 4; ++j) acc[i][j] = (f32x4){0.f, 0.f, 0.f, 0.f};

    const char* at = (const char*)(Ap + (size_t)mb * NKB * 8192);
    const char* bt = (const char*)(Bp + (size_t)nb * NKB * 8192);

    // phase 1: full split (3 products per frag)
    for (int kb = 0; kb < nkb_full; ++kb) {
        const char* atk = at + (size_t)kb * 16384;
        const char* btk = bt + (size_t)kb * 16384;
#pragma unroll
        for (int c = 0; c < 4; ++c) {
            __builtin_amdgcn_global_load_lds(
                (gu32*)(atk + c * 4096 + tid * 16),
                (lu32*)&sb[c * 2048 + wid * 512], 16, 0, 0);
            __builtin_amdgcn_global_load_lds(
                (gu32*)(btk + c * 4096 + tid * 16),
                (lu32*)&sb[8192 + c * 2048 + wid * 512], 16, 0, 0);
        }
        __syncthreads();

        bf16x8 af[2][4], bv[2][4];
#pragma unroll
        for (int hl = 0; hl < 2; ++hl)
#pragma unroll
            for (int m = 0; m < 4; ++m)
                af[hl][m] = *(const bf16x8*)&sb[hl * 4096 + l4 * 1024 + (wr * 64 + m * 16 + l15) * 8];
#pragma unroll
        for (int hl = 0; hl < 2; ++hl)
#pragma unroll
            for (int n = 0; n < 4; ++n)
                bv[hl][n] = *(const bf16x8*)&sb[8192 + hl * 4096 + l4 * 1024 + (wc * 64 + n * 16 + l15) * 8];

#pragma unroll
        for (int m = 0; m < 4; ++m)
#pragma unroll
            for (int n = 0; n < 4; ++n) {
                acc[m][n] = __builtin_amdgcn_mfma_f32_16x16x32_bf16(af[0][m], bv[0][n], acc[m][n], 0, 0, 0);
                acc[m][n] = __builtin_amdgcn_mfma_f32_16x16x32_bf16(af[0][m], bv[1][n], acc[m][n], 0, 0, 0);
                acc[m][n] = __builtin_amdgcn_mfma_f32_16x16x32_bf16(af[1][m], bv[0][n], acc[m][n], 0, 0, 0);
            }
        __syncthreads();
    }

    // phase 2: A-lo known zero (2 products per frag, A-hi load only)
    for (int kb = nkb_full; kb < NKB; ++kb) {
        const char* atk = at + (size_t)kb * 16384;
        const char* btk = bt + (size_t)kb * 16384;
#pragma unroll
        for (int c = 0; c < 2; ++c) {
            __builtin_amdgcn_global_load_lds(
                (gu32*)(atk + c * 4096 + tid * 16),
                (lu32*)&sb[c * 2048 + wid * 512], 16, 0, 0);
        }
#pragma unroll
        for (int c = 0; c < 4; ++c) {
            __builtin_amdgcn_global_load_lds(
                (gu32*)(btk + c * 4096 + tid * 16),
                (lu32*)&sb[8192 + c * 2048 + wid * 512], 16, 0, 0);
        }
        __syncthreads();

        bf16x8 af0[4], bv[2][4];
#pragma unroll
        for (int m = 0; m < 4; ++m)
            af0[m] = *(const bf16x8*)&sb[l4 * 1024 + (wr * 64 + m * 16 + l15) * 8];
#pragma unroll
        for (int hl = 0; hl < 2; ++hl)
#pragma unroll
            for (int n = 0; n < 4; ++n)
                bv[hl][n] = *(const bf16x8*)&sb[8192 + hl * 4096 + l4 * 1024 + (wc * 64 + n * 16 + l15) * 8];

#pragma unroll
        for (int m = 0; m < 4; ++m)
#pragma unroll
            for (int n = 0; n < 4; ++n) {
                acc[m][n] = __builtin_amdgcn_mfma_f32_16x16x32_bf16(af0[m], bv[0][n], acc[m][n], 0, 0, 0);
                acc[m][n] = __builtin_amdgcn_mfma_f32_16x16x32_bf16(af0[m], bv[1][n], acc[m][n], 0, 0, 0);
            }
        __syncthreads();
    }

    const int row_w = mb * 128 + wr * 64;
    const int col_w = nb * 128 + wc * 64;
#pragma unroll
    for (int m = 0; m < 4; ++m) {
#pragma unroll
        for (int n = 0; n < 4; ++n) {
            const int col = col_w + n * 16 + l15;
#pragma unroll
            for (int j = 0; j < 4; ++j) {
                const int row = row_w + m * 16 + l4 * 4 + j;
                if (row < M) {
                    float v = acc[m][n][j];
                    if (bias && col < biasN) v += bias[col];
                    if (do_relu) v = fmaxf(v, 0.f);
                    if (resid) v += resid[(size_t)row * N + col];
                    C[(size_t)row * N + col] = v;
                }
            }
        }
    }
}

// fused GAT (fast path): xlr fp32 [N][2048] (xl cols 0..1023, xr 1024..2047),
// h out bf16 [N][1024].
__global__ __launch_bounds__(256) void gat2_kernel(
    const float* __restrict__ xlr, const int* __restrict__ ssrc,
    const float* __restrict__ sew, const int* __restrict__ offsets,
    const float* __restrict__ loopat, const float* __restrict__ We,
    const float* __restrict__ att, const float* __restrict__ bgat,
    ushort_t* __restrict__ hout)
{
    const int n = blockIdx.x;
    const int base = threadIdx.x * 4;

    const float4 xr4 = *(const float4*)&xlr[(size_t)n * 2048 + 1024 + base];
    const float4 We4 = *(const float4*)&We[base];
    const float4 at4 = *(const float4*)&att[base];

    float M = -INFINITY, D = 0.f;
    float4 acc = make_float4(0.f, 0.f, 0.f, 0.f);

    const int beg = offsets[n], end = offsets[n + 1];
    for (int e = beg; e <= end; ++e) {
        int s; float w;
        if (e < end) { s = ssrc[e]; w = sew[e]; }
        else         { s = n;       w = loopat[n]; }

        const float4 xls = *(const float4*)&xlr[(size_t)s * 2048 + base];
        float m0 = xls.x + xr4.x + w * We4.x;
        float m1 = xls.y + xr4.y + w * We4.y;
        float m2 = xls.z + xr4.z + w * We4.z;
        float m3 = xls.w + xr4.w + w * We4.w;
        m0 = (m0 >= 0.f) ? m0 : 0.2f * m0;
        m1 = (m1 >= 0.f) ? m1 : 0.2f * m1;
        m2 = (m2 >= 0.f) ? m2 : 0.2f * m2;
        m3 = (m3 >= 0.f) ? m3 : 0.2f * m3;
        float p = m0 * at4.x + m1 * at4.y + m2 * at4.z + m3 * at4.w;
#pragma unroll
        for (int o = 32; o >= 1; o >>= 1) p += __shfl_xor(p, o, 64);

        float newM  = fmaxf(M, p);
        float scale = __expf(M - newM);
        float wexp  = __expf(p - newM);
        D     = D * scale + wexp;
        acc.x = acc.x * scale + wexp * xls.x;
        acc.y = acc.y * scale + wexp * xls.y;
        acc.z = acc.z * scale + wexp * xls.z;
        acc.w = acc.w * scale + wexp * xls.w;
        M = newM;
    }

    const float inv = 1.0f / (D + 1e-16f);
    float g0 = acc.x * inv + bgat[base + 0];
    float g1 = acc.y * inv + bgat[base + 1];
    float g2 = acc.z * inv + bgat[base + 2];
    float g3 = acc.w * inv + bgat[base + 3];
    u16x4 hv;
    hv[0] = f2bf_rne((g0 > 0.f) ? g0 : expm1f(g0));
    hv[1] = f2bf_rne((g1 > 0.f) ? g1 : expm1f(g1));
    hv[2] = f2bf_rne((g2 > 0.f) ? g2 : expm1f(g2));
    hv[3] = f2bf_rne((g3 > 0.f) ? g3 : expm1f(g3));
    *(u16x4*)&hout[(size_t)n * 1024 + base] = hv;
}

// agg (fast path): mean of bf16 h[src] rows -> fp32 agg
__global__ __launch_bounds__(256) void agg2_kernel(
    const ushort_t* __restrict__ hb, const int* __restrict__ ssrc,
    const int* __restrict__ offsets, float* __restrict__ aggout)
{
    const int n = blockIdx.x;
    const int base = threadIdx.x * 4;
    float4 a = make_float4(0.f, 0.f, 0.f, 0.f);
    const int beg = offsets[n], end = offsets[n + 1];
    for (int e = beg; e < end; ++e) {
        const u16x4 hv = *(const u16x4*)&hb[(size_t)ssrc[e] * 1024 + base];
        a.x += bf2f(hv[0]); a.y += bf2f(hv[1]);
        a.z += bf2f(hv[2]); a.w += bf2f(hv[3]);
    }
    const float inv = 1.0f / fmaxf((float)(end - beg), 1.0f);
    a.x *= inv; a.y *= inv; a.z *= inv; a.w *= inv;
    *(float4*)&aggout[(size_t)n * 1024 + base] = a;
}

// ---------------------------------------------------------------------------
// LayerNorm over last dim (1280), in-place. 320 threads x float4 per row.
// ---------------------------------------------------------------------------
__global__ __launch_bounds__(320) void ln_kernel(
    float* __restrict__ z, const float* __restrict__ gamma,
    const float* __restrict__ beta)
{
    const int r = blockIdx.x;
    const int t = threadIdx.x;
    const int wave = t >> 6, lane = t & 63;
    __shared__ float red[5];

    float4 v = *(const float4*)&z[(size_t)r * kESM + t * 4];
    float s = v.x + v.y + v.z + v.w;
#pragma unroll
    for (int o = 32; o >= 1; o >>= 1) s += __shfl_xor(s, o, 64);
    if (lane == 0) red[wave] = s;
    __syncthreads();
    s = red[0] + red[1] + red[2] + red[3] + red[4];
    const float mu = s * (1.0f / (float)kESM);

    float dx = v.x - mu, dy = v.y - mu, dz = v.z - mu, dw = v.w - mu;
    float q = dx * dx + dy * dy + dz * dz + dw * dw;
#pragma unroll
    for (int o = 32; o >= 1; o >>= 1) q += __shfl_xor(q, o, 64);
    __syncthreads();
    if (lane == 0) red[wave] = q;
    __syncthreads();
    q = red[0] + red[1] + red[2] + red[3] + red[4];
    const float rstd = rsqrtf(q * (1.0f / (float)kESM) + 1e-5f);

    const float4 g4 = *(const float4*)&gamma[t * 4];
    const float4 b4 = *(const float4*)&beta[t * 4];
    float4 o;
    o.x = dx * rstd * g4.x + b4.x;
    o.y = dy * rstd * g4.y + b4.y;
    o.z = dz * rstd * g4.z + b4.z;
    o.w = dw * rstd * g4.w + b4.w;
    *(float4*)&z[(size_t)r * kESM + t * 4] = o;
}

// ===========================================================================
// FALLBACK PATH (round-2, known-pass): fp32 vector GEMM + fp32 gat/agg
// ===========================================================================
#define BM 128
#define BN 128
#define BK 16

__global__ __launch_bounds__(256) void gemm_kernel(
    const float* __restrict__ A,  const float* __restrict__ B,
    const float* __restrict__ A2, const float* __restrict__ B2,
    const float* __restrict__ bias, const float* __restrict__ resid,
    float* __restrict__ C, int M, int N, int K, int do_relu)
{
    __shared__ float As[BK][BM];
    __shared__ float Bs[BK][BN];

    const int tid = threadIdx.x;
    const int bm = blockIdx.y, bn = blockIdx.x;
    const int row0 = bm * BM, col0 = bn * BN;
    const int tx = tid & 15, ty = tid >> 4;

    float acc[8][8];
#pragma unroll
    for (int i = 0; i < 8; ++i)
#pragma unroll
        for (int j = 0; j < 8; ++j) acc[i][j] = 0.0f;

    const int arow  = tid >> 1;
    const int akoff = (tid & 1) * 8;
    const int bkr   = tid >> 4;
    const int bcol  = (tid & 15) * 8;

    for (int pair = 0; pair < 2; ++pair) {
        const float* Ap = pair ? A2 : A;
        const float* Bp = pair ? B2 : B;
        if (!Ap) break;
        for (int k0 = 0; k0 < K; k0 += BK) {
            float4 a0 = make_float4(0.f, 0.f, 0.f, 0.f);
            float4 a1 = a0;
            int gr = row0 + arow;
            if (gr < M) {
                const float* aptr = Ap + (size_t)gr * K + k0 + akoff;
                a0 = *(const float4*)aptr;
                a1 = *(const float4*)(aptr + 4);
            }
            const float* bptr = Bp + (size_t)(k0 + bkr) * N + col0 + bcol;
            float4 b0 = *(const float4*)bptr;
            float4 b1 = *(const float4*)(bptr + 4);

            __syncthreads();
            As[akoff + 0][arow] = a0.x;
            As[akoff + 1][arow] = a0.y;
            As[akoff + 2][arow] = a0.z;
            As[akoff + 3][arow] = a0.w;
            As[akoff + 4][arow] = a1.x;
            As[akoff + 5][arow] = a1.y;
            As[akoff + 6][arow] = a1.z;
            As[akoff + 7][arow] = a1.w;
            *(float4*)&Bs[bkr][bcol]     = b0;
            *(float4*)&Bs[bkr][bcol + 4] = b1;
            __syncthreads();

#pragma unroll
            for (int kk = 0; kk < BK; ++kk) {
                float4 a0r = *(const float4*)&As[kk][ty * 8];
                float4 a1r = *(const float4*)&As[kk][ty * 8 + 4];
                float4 b0r = *(const float4*)&Bs[kk][tx * 4];
                float4 b1r = *(const float4*)&Bs[kk][64 + tx * 4];
                float ar[8] = {a0r.x, a0r.y, a0r.z, a0r.w, a1r.x, a1r.y, a1r.z, a1r.w};
                float br[8] = {b0r.x, b0r.y, b0r.z, b0r.w, b1r.x, b1r.y, b1r.z, b1r.w};
#pragma unroll
                for (int i = 0; i < 8; ++i)
#pragma unroll
                    for (int j = 0; j < 8; ++j)
                        acc[i][j] = fmaf(ar[i], br[j], acc[i][j]);
            }
        }
    }

#pragma unroll
    for (int i = 0; i < 8; ++i) {
        int gr = row0 + ty * 8 + i;
        if (gr >= M) break;
#pragma unroll
        for (int half = 0; half < 2; ++half) {
            int gc = col0 + half * 64 + tx * 4;
            float4 out;
            float* o = &out.x;
            const float* rrow = resid ? (resid + (size_t)gr * N + gc) : nullptr;
#pragma unroll
            for (int j = 0; j < 4; ++j) {
                float v = acc[i][half * 4 + j];
                if (bias) v += bias[gc + j];
                if (do_relu) v = fmaxf(v, 0.0f);
                if (rrow) v += rrow[j];
                o[j] = v;
            }
            *(float4*)&C[(size_t)gr * N + gc] = out;
        }
    }
}

__global__ __launch_bounds__(256) void gat_kernel(
    const float* __restrict__ xl, const float* __restrict__ xr,
    const int* __restrict__ ssrc, const float* __restrict__ sew,
    const int* __restrict__ offsets, const float* __restrict__ loopat,
    const float* __restrict__ We, const float* __restrict__ att,
    const float* __restrict__ bgat, float* __restrict__ hout)
{
    const int n = blockIdx.x;
    const int base = threadIdx.x * 4;

    const float4 xr4 = *(const float4*)&xr[(size_t)n * kHC + base];
    const float4 We4 = *(const float4*)&We[base];
    const float4 at4 = *(const float4*)&att[base];

    float M = -INFINITY, D = 0.f;
    float4 acc = make_float4(0.f, 0.f, 0.f, 0.f);

    const int beg = offsets[n], end = offsets[n + 1];
    for (int e = beg; e <= end; ++e) {
        int s; float w;
        if (e < end) { s = ssrc[e]; w = sew[e]; }
        else         { s = n;       w = loopat[n]; }

        const float4 xls = *(const float4*)&xl[(size_t)s * kHC + base];
        float m0 = xls.x + xr4.x + w * We4.x;
        float m1 = xls.y + xr4.y + w * We4.y;
        float m2 = xls.z + xr4.z + w * We4.z;
        float m3 = xls.w + xr4.w + w * We4.w;
        m0 = (m0 >= 0.f) ? m0 : 0.2f * m0;
        m1 = (m1 >= 0.f) ? m1 : 0.2f * m1;
        m2 = (m2 >= 0.f) ? m2 : 0.2f * m2;
        m3 = (m3 >= 0.f) ? m3 : 0.2f * m3;
        float p = m0 * at4.x + m1 * at4.y + m2 * at4.z + m3 * at4.w;
#pragma unroll
        for (int o = 32; o >= 1; o >>= 1) p += __shfl_xor(p, o, 64);

        float newM  = fmaxf(M, p);
        float scale = __expf(M - newM);
        float wexp  = __expf(p - newM);
        D     = D * scale + wexp;
        acc.x = acc.x * scale + wexp * xls.x;
        acc.y = acc.y * scale + wexp * xls.y;
        acc.z = acc.z * scale + wexp * xls.z;
        acc.w = acc.w * scale + wexp * xls.w;
        M = newM;
    }

    const float inv = 1.0f / (D + 1e-16f);
    float g0 = acc.x * inv + bgat[base + 0];
    float g1 = acc.y * inv + bgat[base + 1];
    float g2 = acc.z * inv + bgat[base + 2];
    float g3 = acc.w * inv + bgat[base + 3];
    float4 hv;
    hv.x = (g0 > 0.f) ? g0 : expm1f(g0);
    hv.y = (g1 > 0.f) ? g1 : expm1f(g1);
    hv.z = (g2 > 0.f) ? g2 : expm1f(g2);
    hv.w = (g3 > 0.f) ? g3 : expm1f(g3);
    *(float4*)&hout[(size_t)n * kHC + base] = hv;
}

__global__ __launch_bounds__(256) void agg_kernel(
    const float* __restrict__ h, const int* __restrict__ ssrc,
    const int* __restrict__ offsets, float* __restrict__ aggout)
{
    const int n = blockIdx.x;
    const int base = threadIdx.x * 4;
    float4 a = make_float4(0.f, 0.f, 0.f, 0.f);
    const int beg = offsets[n], end = offsets[n + 1];
    for (int e = beg; e < end; ++e) {
        const float4 hv = *(const float4*)&h[(size_t)ssrc[e] * kHC + base];
        a.x += hv.x; a.y += hv.y; a.z += hv.z; a.w += hv.w;
    }
    const float inv = 1.0f / fmaxf((float)(end - beg), 1.0f);
    a.x *= inv; a.y *= inv; a.z *= inv; a.w *= inv;
    *(float4*)&aggout[(size_t)n * kHC + base] = a;
}

// ---------------------------------------------------------------------------
extern "C" void kernel_launch(void* const* d_in, const int* in_sizes, int n_in,
                              void* d_out, int out_size, void* d_ws, size_t ws_size,
                              hipStream_t stream)
{
    const float* x     = (const float*)d_in[0];
    const int*   ei    = (const int*)  d_in[1];
    const float* ew    = (const float*)d_in[2];
    const float* Wl    = (const float*)d_in[3];
    const float* bl    = (const float*)d_in[4];
    const float* Wr    = (const float*)d_in[5];
    const float* We    = (const float*)d_in[6];
    const float* att   = (const float*)d_in[7];
    const float* bgat  = (const float*)d_in[8];
    const float* Wsl   = (const float*)d_in[9];
    const float* bsl   = (const float*)d_in[10];
    const float* Wsr   = (const float*)d_in[11];
    const float* gamma = (const float*)d_in[12];
    const float* beta  = (const float*)d_in[13];
    const int* src = ei;
    const int* dst = ei + kE;
    char* ws = (char*)d_ws;

    // fast-path layout (bytes)
    const size_t SZ_XPACK = (size_t)157 * 40 * 16384;        // 102,891,520
    const size_t SZ_XLR   = (size_t)kN * 2048 * 4;           // 163,840,000
    const size_t SZ_HBUF  = (size_t)kN * 1024 * 2;           //  40,960,000
    const size_t SZ_B1    = (size_t)16 * 40 * 16384;         //  10,485,760
    const size_t SZ_B2    = (size_t)10 * 64 * 16384;         //  10,485,760
    const size_t OFF_XLR  = SZ_XPACK;
    const size_t OFF_HBUF = OFF_XLR + SZ_XLR;
    const size_t OFF_B1   = OFF_HBUF + SZ_HBUF;
    const size_t OFF_B2   = OFF_B1 + SZ_B1;
    size_t off = OFF_B2 + SZ_B2;
    auto salloc = [&](size_t bytes) -> void* {
        void* p = ws + off;
        off = (off + bytes + 255) & ~(size_t)255;
        return p;
    };
    int*   deg    = (int*)  salloc((size_t)kN * 4);
    int*   cnt    = (int*)  salloc((size_t)kN * 4);
    int*   offs   = (int*)  salloc((size_t)(kN + 1) * 4);
    float* loopat = (float*)salloc((size_t)kN * 4);
    int*   ssrc   = (int*)  salloc((size_t)kE * 4);
    float* sew    = (float*)salloc((size_t)kE * 4);
    const size_t FAST_TOTAL = off;

    if (ws_size >= FAST_TOTAL) {
        // ------------------ FAST PATH ------------------
        ushort_t* xpack = (ushort_t*)(ws);
        float*    xlr   = (float*)   (ws + OFF_XLR);
        ushort_t* hbuf  = (ushort_t*)(ws + OFF_HBUF);
        ushort_t* b1p   = (ushort_t*)(ws + OFF_B1);
        ushort_t* b2p   = (ushort_t*)(ws + OFF_B2);
        // aliases (lifetimes verified): agg over tail of dead xlr; apack over dead xpack+xlr head
        float*    aggb  = (float*)   (ws + OFF_HBUF - (size_t)kN * 1024 * 4);
        ushort_t* apack = (ushort_t*)(ws);

        hipMemsetAsync(deg,    0, (size_t)kN * 4, stream);
        hipMemsetAsync(cnt,    0, (size_t)kN * 4, stream);
        hipMemsetAsync(loopat, 0, (size_t)kN * 4, stream);

        deg_kernel <<<(kE + 255) / 256, 256, 0, stream>>>(dst, ew, deg, loopat);
        scan_kernel<<<1, 256, 0, stream>>>(deg, loopat, offs);
        sort_kernel<<<(kE + 255) / 256, 256, 0, stream>>>(src, dst, ew, offs, cnt, ssrc, sew);

        pack_a_kernel<<<dim3(40, 157), 512, 0, stream>>>(x, kN, kESM, 40, xpack);
        pack_b_kernel<<<dim3(40, 16), 512, 0, stream>>>(Wl, Wr, 2048, 1024, 0, b1p);
        pack_b_kernel<<<dim3(64, 10), 512, 0, stream>>>(Wsl, Wsr, 1280, 1024, 1, b2p);

        gemm_mfma<<<dim3(16, 157), 256, 0, stream>>>(xpack, b1p, bl, 1024,
                                                     nullptr, xlr, kN, 2048, 40, 40, 0);

        gat2_kernel<<<kN, 256, 0, stream>>>(xlr, ssrc, sew, offs, loopat,
                                            We, att, bgat, hbuf);
        agg2_kernel<<<kN, 256, 0, stream>>>(hbuf, ssrc, offs, aggb);

        pack_a2_kernel<<<dim3(64, 157), 512, 0, stream>>>(aggb, hbuf, kN, apack);

        gemm_mfma<<<dim3(10, 157), 256, 0, stream>>>(apack, b2p, bsl, 1280,
                                                     x, (float*)d_out, kN, 1280, 64, 32, 1);

        ln_kernel<<<kN, 320, 0, stream>>>((float*)d_out, gamma, beta);
    } else {
        // ------------------ FALLBACK (round-2) ------------------
        size_t foff = 0;
        auto falloc = [&](size_t bytes) -> void* {
            void* p = ws + foff;
            foff = (foff + bytes + 255) & ~(size_t)255;
            return p;
        };
        int*   fdeg    = (int*)  falloc((size_t)kN * 4);
        int*   fcnt    = (int*)  falloc((size_t)kN * 4);
        int*   foffs   = (int*)  falloc((size_t)(kN + 1) * 4);
        float* floopat = (float*)falloc((size_t)kN * 4);
        int*   fssrc   = (int*)  falloc((size_t)kE * 4);
        float* fsew    = (float*)falloc((size_t)kE * 4);
        float* bufA    = (float*)falloc((size_t)kN * kHC * 4);
        float* bufB    = (float*)falloc((size_t)kN * kHC * 4);

        hipMemsetAsync(fdeg,    0, (size_t)kN * 4, stream);
        hipMemsetAsync(fcnt,    0, (size_t)kN * 4, stream);
        hipMemsetAsync(floopat, 0, (size_t)kN * 4, stream);

        deg_kernel <<<(kE + 255) / 256, 256, 0, stream>>>(dst, ew, fdeg, floopat);
        scan_kernel<<<1, 256, 0, stream>>>(fdeg, floopat, foffs);
        sort_kernel<<<(kE + 255) / 256, 256, 0, stream>>>(src, dst, ew, foffs, fcnt, fssrc, fsew);

        dim3 g1(kHC / BN, (kN + BM - 1) / BM);
        gemm_kernel<<<g1, 256, 0, stream>>>(x, Wl, nullptr, nullptr, bl, nullptr,
                                            bufA, kN, kHC, kESM, 0);
        gemm_kernel<<<g1, 256, 0, stream>>>(x, Wr, nullptr, nullptr, nullptr, nullptr,
                                            bufB, kN, kHC, kESM, 0);

        gat_kernel<<<kN, 256, 0, stream>>>(bufA, bufB, fssrc, fsew, foffs, floopat,
                                           We, att, bgat, bufB);
        agg_kernel<<<kN, 256, 0, stream>>>(bufB, fssrc, foffs, bufA);

        dim3 g2(kESM / BN, (kN + BM - 1) / BM);
        gemm_kernel<<<g2, 256, 0, stream>>>(bufA, Wsl, bufB, Wsr, bsl, x,
                                            (float*)d_out, kN, kESM, kHC, 1);

        ln_kernel<<<kN, 320, 0, stream>>>((float*)d_out, gamma, beta);
    }
}